// Round 11
// baseline (50.112 us; speedup 1.0000x reference)
//
#include <hip/hip_runtime.h>
#include <hip/hip_fp16.h>

#define BB 8
#define HH 512
#define WW 512
#define HW (HH * WW)
#define STRIP 8    // rows marched per thread

__device__ __forceinline__ int reflect512(int v) {
    v = v < 0 ? -v : v;
    return v >= 512 ? 1022 - v : v;
}

// Register-rolling column march with packed-f16 tap math: each __half2 op
// processes 2 window columns. Window is 7 rows x 8 cols (col 7 = padding
// whose spatial log-weight is -1000 -> exp2 underflows to 0, self-masking).
// NOTE: min-waves stays at 2 — (256,4) forced VGPR<=64 and spilled the whole
// window to scratch (R9: WRITE_SIZE 262 MB, 128 us). Let demand float.
__global__ __launch_bounds__(256, 2) void bilateral_h2(const float* __restrict__ in,
                                                       float* __restrict__ out) {
    const int blk   = blockIdx.x;
    const int b     = blk >> 7;          // 128 blocks per image
    const int rem   = blk & 127;
    const int strip = rem >> 1;          // 0..63
    const int xh    = rem & 1;
    const int x     = xh * 256 + threadIdx.x;
    const int ys    = strip * STRIP;

    const float* __restrict__ p0 = in + (size_t)b * 3 * HW;
    const float* __restrict__ p1 = p0 + HW;
    const float* __restrict__ p2 = p1 + HW;

    // reflected column indices (cols x-3 .. x+4; col 7 is padding but loads a
    // valid reflected address)
    int colo[8];
    #pragma unroll
    for (int c = 0; c < 8; ++c) colo[c] = reflect512(x - 3 + c);

    // log2 spatial weights (unnormalized; normalization cancels in num/den)
    const float ls7[7] = {-0.01472138f, -0.00654284f, -0.00163571f, 0.f,
                          -0.00163571f, -0.00654284f, -0.01472138f};
    const float lsx[8] = {-0.01472138f, -0.00654284f, -0.00163571f, 0.f,
                          -0.00163571f, -0.00654284f, -0.01472138f, -1000.0f};
    const __half2 k2 = __float2half2_rn(-0.00721347520445f);  // (-0.5/100)*log2(e)

    // rolling window: slot (k+j)%7 holds image row ys+k-3+j at step k.
    // pair i = cols (2i, 2i+1) packed low/high.
    __half2 w0[7][4], w1[7][4], w2[7][4];
    #pragma unroll
    for (int j = 0; j < 7; ++j) {
        int rb = reflect512(ys - 3 + j) * WW;
        #pragma unroll
        for (int i = 0; i < 4; ++i) {
            int oa = rb + colo[2 * i], ob = rb + colo[2 * i + 1];
            w0[j][i] = __floats2half2_rn(p0[oa], p0[ob]);
            w1[j][i] = __floats2half2_rn(p1[oa], p1[ob]);
            w2[j][i] = __floats2half2_rn(p2[oa], p2[ob]);
        }
    }

    #pragma unroll
    for (int k = 0; k < STRIP; ++k) {
        // prefetch next window row (hidden under the tap block)
        __half2 t0[4], t1[4], t2[4];
        if (k < STRIP - 1) {
            int rb = reflect512(ys + k + 4) * WW;
            #pragma unroll
            for (int i = 0; i < 4; ++i) {
                int oa = rb + colo[2 * i], ob = rb + colo[2 * i + 1];
                t0[i] = __floats2half2_rn(p0[oa], p0[ob]);
                t1[i] = __floats2half2_rn(p1[oa], p1[ob]);
                t2[i] = __floats2half2_rn(p2[oa], p2[ob]);
            }
        }

        const int cs = (k + 3) % 7;                  // compile-time
        // center = col 3 = high half of pair 1, broadcast to both halves
        const __half2 c0 = __high2half2(w0[cs][1]);
        const __half2 c1 = __high2half2(w1[cs][1]);
        const __half2 c2 = __high2half2(w2[cs][1]);

        // even/odd-row split accumulators (limits f16 magnitude/rounding)
        __half2 a0[2] = {__float2half2_rn(0.f), __float2half2_rn(0.f)};
        __half2 a1[2] = {__float2half2_rn(0.f), __float2half2_rn(0.f)};
        __half2 a2[2] = {__float2half2_rn(0.f), __float2half2_rn(0.f)};
        __half2 ad[2] = {__float2half2_rn(0.f), __float2half2_rn(0.f)};

        #pragma unroll
        for (int j = 0; j < 7; ++j) {
            const int s = (k + j) % 7;               // compile-time
            const int h = j & 1;
            #pragma unroll
            for (int i = 0; i < 4; ++i) {
                const __half2 lw = __floats2half2_rn(ls7[j] + lsx[2 * i],
                                                     ls7[j] + lsx[2 * i + 1]);  // folded
                __half2 q0 = w0[s][i], q1 = w1[s][i], q2 = w2[s][i];
                __half2 d  = __habs2(__hsub2(q0, c0));
                d = __hadd2(d, __habs2(__hsub2(q1, c1)));
                d = __hadd2(d, __habs2(__hsub2(q2, c2)));
                __half2 wt = h2exp2(__hfma2(k2, __hmul2(d, d), lw));
                a0[h] = __hfma2(wt, q0, a0[h]);
                a1[h] = __hfma2(wt, q1, a1[h]);
                a2[h] = __hfma2(wt, q2, a2[h]);
                ad[h] = __hadd2(ad[h], wt);
            }
        }

        // reduce: both halves of both parities, in f32
        float2 f0a = __half22float2(a0[0]), f0b = __half22float2(a0[1]);
        float2 f1a = __half22float2(a1[0]), f1b = __half22float2(a1[1]);
        float2 f2a = __half22float2(a2[0]), f2b = __half22float2(a2[1]);
        float2 fda = __half22float2(ad[0]), fdb = __half22float2(ad[1]);
        float n0 = f0a.x + f0a.y + f0b.x + f0b.y;
        float n1 = f1a.x + f1a.y + f1b.x + f1b.y;
        float n2 = f2a.x + f2a.y + f2b.x + f2b.y;
        float dn = fda.x + fda.y + fdb.x + fdb.y;

        const float inv = 1.0f / dn;
        size_t ob = (size_t)b * 3 * HW + (size_t)(ys + k) * WW + x;
        out[ob]          = n0 * inv;
        out[ob + HW]     = n1 * inv;
        out[ob + 2 * HW] = n2 * inv;

        if (k < STRIP - 1) {                         // rotate in the new row
            const int ns = k % 7;
            #pragma unroll
            for (int i = 0; i < 4; ++i) {
                w0[ns][i] = t0[i]; w1[ns][i] = t1[i]; w2[ns][i] = t2[i];
            }
        }
    }
}

extern "C" void kernel_launch(void* const* d_in, const int* in_sizes, int n_in,
                              void* d_out, int out_size, void* d_ws, size_t ws_size,
                              hipStream_t stream) {
    const float* in = (const float*)d_in[0];
    float* out = (float*)d_out;
    int blocks = BB * (WW / 256) * (HH / STRIP);   // 8 * 2 * 64 = 1024
    bilateral_h2<<<blocks, 256, 0, stream>>>(in, out);
}